// Round 1
// baseline (104.266 us; speedup 1.0000x reference)
//
#include <hip/hip_runtime.h>
#include <hip/hip_bf16.h>

// Piecewise GELU (tanh-approx, clamped at |x|=3), fp32 in/out.
// Memory-bound elementwise op: float4 vectorized grid-stride loop.

#define SQRT_2_OVER_PI 0.7978845608028654f
#define GELU_COEF 0.044715f
#define CLAMP_V 3.0f

__device__ __forceinline__ float pgelu(float x) {
    // Clamp the value fed into the tanh branch so exp never overflows;
    // outside [-3,3] the piecewise selects override this value anyway.
    float xc = fminf(fmaxf(x, -CLAMP_V), CLAMP_V);
    float inner = SQRT_2_OVER_PI * (xc + GELU_COEF * xc * xc * xc);
    // tanh(y) = (exp(2y)-1)/(exp(2y)+1); |2*inner| <= 6.72 here, exp is safe.
    float e = __expf(2.0f * inner);
    float t = (e - 1.0f) / (e + 1.0f);
    float mid = 0.5f * xc * (1.0f + t);
    // piecewise: x <= -3 -> 0 ; x >= 3 -> x ; else tanh-GELU
    float out = (x <= -CLAMP_V) ? 0.0f : mid;
    out = (x >= CLAMP_V) ? x : out;
    return out;
}

__global__ void pgelu_kernel_v4(const float4* __restrict__ in,
                                float4* __restrict__ out, int n4) {
    int stride = gridDim.x * blockDim.x;
    for (int i = blockIdx.x * blockDim.x + threadIdx.x; i < n4; i += stride) {
        float4 v = in[i];
        float4 r;
        r.x = pgelu(v.x);
        r.y = pgelu(v.y);
        r.z = pgelu(v.z);
        r.w = pgelu(v.w);
        out[i] = r;
    }
}

__global__ void pgelu_kernel_tail(const float* __restrict__ in,
                                  float* __restrict__ out, int start, int n) {
    int i = start + blockIdx.x * blockDim.x + threadIdx.x;
    if (i < n) out[i] = pgelu(in[i]);
}

extern "C" void kernel_launch(void* const* d_in, const int* in_sizes, int n_in,
                              void* d_out, int out_size, void* d_ws, size_t ws_size,
                              hipStream_t stream) {
    const float* in = (const float*)d_in[0];
    float* out = (float*)d_out;
    int n = in_sizes[0];
    int n4 = n / 4;

    const int block = 256;
    // Memory-bound: cap grid at ~8 blocks/CU x 256 CUs, grid-stride the rest.
    int grid = (n4 + block - 1) / block;
    if (grid > 2048) grid = 2048;
    if (grid < 1) grid = 1;

    pgelu_kernel_v4<<<grid, block, 0, stream>>>((const float4*)in, (float4*)out, n4);

    int rem = n - n4 * 4;
    if (rem > 0) {
        pgelu_kernel_tail<<<1, 64, 0, stream>>>(in, out, n4 * 4, n);
    }
}

// Round 2
// 99.302 us; speedup vs baseline: 1.0500x; 1.0500x over previous
//
#include <hip/hip_runtime.h>
#include <hip/hip_bf16.h>

// Piecewise GELU (tanh-approx, clamped at |x|=3), fp32 in/out.
// HBM-bound elementwise stream: float4 nontemporal loads/stores,
// 2x unrolled grid-stride, sigmoid-form GELU with fast rcp.

#define SQRT_2_OVER_PI 0.7978845608028654f
#define GELU_COEF 0.044715f
#define CLAMP_V 3.0f

typedef float f32x4 __attribute__((ext_vector_type(4)));

__device__ __forceinline__ float pgelu(float x) {
    // Clamp the tanh-branch input; outside [-3,3] the selects override it.
    float xc = fminf(fmaxf(x, -CLAMP_V), CLAMP_V);
    float inner = SQRT_2_OVER_PI * (xc + GELU_COEF * xc * xc * xc);
    // 0.5*x*(1+tanh(inner)) == x * sigmoid(2*inner) == x / (1 + exp(-2*inner))
    // |2*inner| <= 6.72 -> exp in [1.2e-3, 8.3e2], safe.
    float e = __expf(-2.0f * inner);
    float mid = xc * __builtin_amdgcn_rcpf(1.0f + e);
    float out = (x <= -CLAMP_V) ? 0.0f : mid;
    out = (x >= CLAMP_V) ? x : out;
    return out;
}

__device__ __forceinline__ f32x4 pgelu4(f32x4 v) {
    f32x4 r;
    r.x = pgelu(v.x);
    r.y = pgelu(v.y);
    r.z = pgelu(v.z);
    r.w = pgelu(v.w);
    return r;
}

__global__ void pgelu_kernel_v4(const f32x4* __restrict__ in,
                                f32x4* __restrict__ out, int n4) {
    int stride = gridDim.x * blockDim.x;
    int i = blockIdx.x * blockDim.x + threadIdx.x;
    // 2x unroll at stride distance: both loads fully coalesced, independent.
    for (; i + stride < n4; i += 2 * stride) {
        f32x4 a = __builtin_nontemporal_load(&in[i]);
        f32x4 b = __builtin_nontemporal_load(&in[i + stride]);
        f32x4 ra = pgelu4(a);
        f32x4 rb = pgelu4(b);
        __builtin_nontemporal_store(ra, &out[i]);
        __builtin_nontemporal_store(rb, &out[i + stride]);
    }
    for (; i < n4; i += stride) {
        f32x4 a = __builtin_nontemporal_load(&in[i]);
        __builtin_nontemporal_store(pgelu4(a), &out[i]);
    }
}

__global__ void pgelu_kernel_tail(const float* __restrict__ in,
                                  float* __restrict__ out, int start, int n) {
    int i = start + blockIdx.x * blockDim.x + threadIdx.x;
    if (i < n) out[i] = pgelu(in[i]);
}

extern "C" void kernel_launch(void* const* d_in, const int* in_sizes, int n_in,
                              void* d_out, int out_size, void* d_ws, size_t ws_size,
                              hipStream_t stream) {
    const float* in = (const float*)d_in[0];
    float* out = (float*)d_out;
    int n = in_sizes[0];
    int n4 = n / 4;

    const int block = 256;
    // Memory-bound: ~8 blocks/CU x 256 CUs, grid-stride the rest.
    int grid = (n4 + block - 1) / block;
    if (grid > 2048) grid = 2048;
    if (grid < 1) grid = 1;

    pgelu_kernel_v4<<<grid, block, 0, stream>>>((const f32x4*)in, (f32x4*)out, n4);

    int rem = n - n4 * 4;
    if (rem > 0) {
        pgelu_kernel_tail<<<1, 64, 0, stream>>>(in, out, n4 * 4, n);
    }
}